// Round 1
// baseline (21490.793 us; speedup 1.0000x reference)
//
#include <hip/hip_runtime.h>
#include <cstdint>
#include <cstddef>

// Problem dims
#define Vv 32000
#define Ee 512
#define Hh 512
#define Bb 32
#define Ss 128

typedef __bf16 bf16x8 __attribute__((ext_vector_type(8)));
typedef float  f32x4  __attribute__((ext_vector_type(4)));

__device__ __forceinline__ float b2f(unsigned short u) {
  union { unsigned int i; float f; } v; v.i = ((unsigned int)u) << 16; return v.f;
}
__device__ __forceinline__ unsigned short f2b(float f) {
  union { float f; unsigned int i; } v; v.f = f;
  unsigned int r = v.i + 0x7FFFu + ((v.i >> 16) & 1u);
  return (unsigned short)(r >> 16);
}
__device__ __forceinline__ float sigm(float x) { return 1.f / (1.f + __expf(-x)); }

// ---------------- prep kernels ----------------

__global__ void cast_bf16(const float* __restrict__ src, unsigned short* __restrict__ dst, int n4) {
  int i = blockIdx.x * 256 + threadIdx.x;
  if (i >= n4) return;
  float4 v = reinterpret_cast<const float4*>(src)[i];
  ushort4 o;
  o.x = f2b(v.x); o.y = f2b(v.y); o.z = f2b(v.z); o.w = f2b(v.w);
  reinterpret_cast<ushort4*>(dst)[i] = o;
}

// dst[(c + rowOff)*dstStride + r] = src[r*C + c];  R,C multiples of 32
__global__ void transpose_f32(const float* __restrict__ src, float* __restrict__ dst,
                              int R, int C, int dstStride, int rowOff) {
  __shared__ float tile[32][33];
  int tx = threadIdx.x & 31, ty = threadIdx.x >> 5;  // ty 0..7
  int c0 = blockIdx.x * 32, r0 = blockIdx.y * 32;
#pragma unroll
  for (int i = 0; i < 32; i += 8) {
    tile[ty + i][tx] = src[(size_t)(r0 + ty + i) * C + (c0 + tx)];
  }
  __syncthreads();
#pragma unroll
  for (int i = 0; i < 32; i += 8) {
    dst[(size_t)(c0 + ty + i + rowOff) * dstStride + (r0 + tx)] = tile[tx][ty + i];
  }
}

// emb_bf16[s][b][e] = bf16(table[target[b][s]][e]) ; grid 4096 blocks x 128 thr
__global__ void embed_gather(const int* __restrict__ target, const float* __restrict__ table,
                             unsigned short* __restrict__ emb) {
  int sb = blockIdx.x;           // sb = s*32 + b
  int s = sb >> 5, b = sb & 31;
  int tok = target[b * Ss + s];
  float4 v = reinterpret_cast<const float4*>(table + (size_t)tok * Ee)[threadIdx.x];
  ushort4 o;
  o.x = f2b(v.x); o.y = f2b(v.y); o.z = f2b(v.z); o.w = f2b(v.w);
  reinterpret_cast<ushort4*>(emb + (size_t)sb * Ee)[threadIdx.x] = o;
}

// initial hidden -> parity 1 buffers. context: [4][32][512], rows 0,1 = layer0 (d0,d1), rows 2,3 = layer1
__global__ void init_h(const float* __restrict__ context, float* __restrict__ h0buf, float* __restrict__ h1buf) {
  int i = blockIdx.x * 256 + threadIdx.x;  // 0..32767
  if (i < 32768) {
    h0buf[32768 + i] = context[i];
    h1buf[32768 + i] = context[32768 + i];
  }
}

// ---------------- bf16 MFMA GEMM: C = A * B^T + bias ----------------
// A: [M][K] bf16 row-major (M in tiles of 128 via grid.x)
// Bm: [N][K] bf16 row-major (N tiles via grid.y)
// MODE 0: C bf16 [M][ldc], row = A-row; z via sBz/sCz/sBiasz (grid.z)
// MODE 1: C f32, row remap r=(s*32+b) -> out row (b*128+s), ldc=Vv
template <int MODE>
__global__ __launch_bounds__(256, 2) void gemm_nt(
    const unsigned short* __restrict__ A, const unsigned short* __restrict__ Bm,
    const float* __restrict__ bias, void* __restrict__ Cout,
    int K, int ldc, size_t sBz, size_t sCz, size_t sBiasz) {
  int z = blockIdx.z;
  Bm += z * sBz;
  bias += z * sBiasz;

  __shared__ __align__(16) unsigned short As[128 * 64];
  __shared__ __align__(16) unsigned short Bs[128 * 64];

  int t = threadIdx.x;
  int m0 = blockIdx.x * 128, n0 = blockIdx.y * 128;
  int wave = t >> 6, lane = t & 63;
  int wr = wave >> 1, wc = wave & 1;

  f32x4 acc[4][4] = {};

  int kt = K >> 6;
  for (int ks = 0; ks < kt; ++ks) {
    int k0 = ks << 6;
#pragma unroll
    for (int c = 0; c < 4; ++c) {
      int v = c * 256 + t;
      int row = v >> 3, col = (v & 7) * 8;
      uint4 da = *reinterpret_cast<const uint4*>(A + (size_t)(m0 + row) * K + k0 + col);
      uint4 db = *reinterpret_cast<const uint4*>(Bm + (size_t)(n0 + row) * K + k0 + col);
      *reinterpret_cast<uint4*>(As + v * 8) = da;
      *reinterpret_cast<uint4*>(Bs + v * 8) = db;
    }
    __syncthreads();
#pragma unroll
    for (int kk = 0; kk < 2; ++kk) {
      bf16x8 af[4], bfr[4];
      int lrow = lane & 15, lk = kk * 32 + (lane >> 4) * 8;
#pragma unroll
      for (int m = 0; m < 4; ++m)
        af[m] = *reinterpret_cast<const bf16x8*>(As + (wr * 64 + m * 16 + lrow) * 64 + lk);
#pragma unroll
      for (int n = 0; n < 4; ++n)
        bfr[n] = *reinterpret_cast<const bf16x8*>(Bs + (wc * 64 + n * 16 + lrow) * 64 + lk);
#pragma unroll
      for (int m = 0; m < 4; ++m)
#pragma unroll
        for (int n = 0; n < 4; ++n)
          acc[m][n] = __builtin_amdgcn_mfma_f32_16x16x32_bf16(af[m], bfr[n], acc[m][n], 0, 0, 0);
    }
    __syncthreads();
  }

  int lrow4 = (lane >> 4) * 4, lcol = lane & 15;
#pragma unroll
  for (int m = 0; m < 4; ++m) {
    int rbase = m0 + wr * 64 + m * 16 + lrow4;
#pragma unroll
    for (int n = 0; n < 4; ++n) {
      int col = n0 + wc * 64 + n * 16 + lcol;
      float bv = bias[col];
#pragma unroll
      for (int j = 0; j < 4; ++j) {
        int r = rbase + j;
        float vv = acc[m][n][j] + bv;
        if (MODE == 0) {
          ((unsigned short*)Cout)[z * sCz + (size_t)r * ldc + col] = f2b(vv);
        } else {
          int b = r & 31, s = r >> 5;
          ((float*)Cout)[(size_t)(b * Ss + s) * ldc + col] = vv;
        }
      }
    }
  }
}

// ---------------- recurrence phase kernel ----------------
// phase p: blocks [0,256) do layer0 for t=p (if p<S); blocks [256,768) do layer1 for t=p-1 (if p>=1)
// h buffers: [parity][d][b][j] fp32, parity = t&1 holds state AFTER step t; initial state in parity 1.
__global__ __launch_bounds__(256) void phase_kernel(
    int p,
    const unsigned short* __restrict__ gi0,
    const float* __restrict__ wThh0, const float* __restrict__ wT1,
    const float* __restrict__ b_hh0, const float* __restrict__ b_ih1, const float* __restrict__ b_hh1,
    float* __restrict__ h0buf, float* __restrict__ h1buf,
    unsigned short* __restrict__ outs) {
  __shared__ float red[768];
  int blk = blockIdx.x;
  if (blk < 256) {
    if (p >= Ss) return;
    int t_ = p;
    int gid = blk * 256 + threadIdx.x;  // 0..65535
    int kh = gid & 1;
    int o = gid >> 1;                   // d*16384 + b*512 + j
    int j = o & 511, b = (o >> 9) & 31, d = o >> 14;
    const float* w = wThh0 + (size_t)d * 512 * 1536;
    const float* hp = h0buf + (size_t)((t_ + 1) & 1) * 32768 + d * 16384 + b * 512;
    float ar = 0.f, az = 0.f, an = 0.f;
    int h0i = kh * 256;
    const float* wp = w + (size_t)h0i * 1536 + j;
    const float* hpp = hp + h0i;
#pragma unroll 8
    for (int h = 0; h < 256; ++h) {
      float hv = hpp[h];
      ar = fmaf(hv, wp[0], ar);
      az = fmaf(hv, wp[512], az);
      an = fmaf(hv, wp[1024], an);
      wp += 1536;
    }
    int oo = threadIdx.x >> 1;
    if (kh) {
      red[oo * 3 + 0] = ar; red[oo * 3 + 1] = az; red[oo * 3 + 2] = an;
    }
    __syncthreads();
    if (!kh) {
      ar += red[oo * 3 + 0]; az += red[oo * 3 + 1]; an += red[oo * 3 + 2];
      const unsigned short* gi = gi0 + ((size_t)d * Ss + t_) * Bb * 1536 + (size_t)b * 1536 + j;
      float gir = b2f(gi[0]), giz = b2f(gi[512]), gin = b2f(gi[1024]);
      const float* bh = b_hh0 + d * 1536 + j;
      float hr = ar + bh[0], hz = az + bh[512], hn = an + bh[1024];
      float r = sigm(gir + hr);
      float zg = sigm(giz + hz);
      float n = tanhf(gin + r * hn);
      float hprev = hp[j];
      float hnew = (1.f - zg) * n + zg * hprev;
      h0buf[(size_t)(t_ & 1) * 32768 + d * 16384 + b * 512 + j] = hnew;
    }
  } else {
    if (p < 1) return;
    int t_ = p - 1;
    int gid = (blk - 256) * 256 + threadIdx.x;  // 0..131071
    int q = gid & 3;
    int o = gid >> 2;
    int j = o & 511, b = (o >> 9) & 31, d = o >> 14;
    const float* w = wT1 + (size_t)d * 1536 * 1536;
    const float* xsrc = h0buf + (size_t)(t_ & 1) * 32768;  // x1[b][c] = h0cur[c>>9][b][c&511]
    const float* hp = h1buf + (size_t)((t_ + 1) & 1) * 32768 + d * 16384 + b * 512;
    float ar = 0.f, az = 0.f, ani = 0.f, anh = 0.f;
    int cbeg = q * 384, cend = cbeg + 384;
    int cmid = min(max(1024, cbeg), cend);
    const float* wp = w + (size_t)cbeg * 1536 + j;
#pragma unroll 4
    for (int c = cbeg; c < cmid; ++c) {
      float xv = xsrc[((c >> 9) << 14) + (b << 9) + (c & 511)];
      ar = fmaf(xv, wp[0], ar);
      az = fmaf(xv, wp[512], az);
      ani = fmaf(xv, wp[1024], ani);
      wp += 1536;
    }
#pragma unroll 4
    for (int c = cmid; c < cend; ++c) {
      float hv = hp[c - 1024];
      ar = fmaf(hv, wp[0], ar);
      az = fmaf(hv, wp[512], az);
      anh = fmaf(hv, wp[1024], anh);
      wp += 1536;
    }
    int oo = threadIdx.x >> 2;
    if (q) {
      float* rr = red + oo * 12 + (q - 1) * 4;
      rr[0] = ar; rr[1] = az; rr[2] = ani; rr[3] = anh;
    }
    __syncthreads();
    if (!q) {
#pragma unroll
      for (int qq = 0; qq < 3; ++qq) {
        const float* rr = red + oo * 12 + qq * 4;
        ar += rr[0]; az += rr[1]; ani += rr[2]; anh += rr[3];
      }
      const float* bi = b_ih1 + d * 1536 + j;
      const float* bh = b_hh1 + d * 1536 + j;
      float r = sigm(ar + bi[0] + bh[0]);
      float zg = sigm(az + bi[512] + bh[512]);
      float n = tanhf((ani + bi[1024]) + r * (anh + bh[1024]));
      float hprev = hp[j];
      float hnew = (1.f - zg) * n + zg * hprev;
      h1buf[(size_t)(t_ & 1) * 32768 + d * 16384 + b * 512 + j] = hnew;
      outs[((size_t)t_ * Bb + b) * 1024 + d * 512 + j] = f2b(hnew);
    }
  }
}

// ---------------- fused online logsumexp + subtract ----------------
__global__ __launch_bounds__(256) void lse_sub(float* __restrict__ out) {
  int row = blockIdx.x;
  float* rp = out + (size_t)row * Vv;
  int t = threadIdx.x;
  float m = -1e30f, ssum = 0.f;
  for (int i = t; i < Vv; i += 256) {
    float x = rp[i];
    if (x <= m) {
      ssum += __expf(x - m);
    } else {
      ssum = ssum * __expf(m - x) + 1.f;
      m = x;
    }
  }
  __shared__ float sm[256], ss[256];
  sm[t] = m; ss[t] = ssum;
  __syncthreads();
  for (int off = 128; off > 0; off >>= 1) {
    if (t < off) {
      float m2 = sm[t + off], s2 = ss[t + off];
      float M = fmaxf(sm[t], m2);
      ss[t] = ss[t] * __expf(sm[t] - M) + s2 * __expf(m2 - M);
      sm[t] = M;
    }
    __syncthreads();
  }
  float lse = sm[0] + __logf(ss[0]);
  for (int i = t; i < Vv; i += 256) rp[i] = rp[i] - lse;
}

// ---------------- host ----------------

extern "C" void kernel_launch(void* const* d_in, const int* in_sizes, int n_in,
                              void* d_out, int out_size, void* d_ws, size_t ws_size,
                              hipStream_t stream) {
  (void)in_sizes; (void)n_in; (void)out_size; (void)ws_size;
  const int*   target  = (const int*)  d_in[0];
  const float* context = (const float*)d_in[2];
  const float* table   = (const float*)d_in[3];
  const float* w_ih0   = (const float*)d_in[4];
  const float* w_hh0   = (const float*)d_in[5];
  const float* b_ih0   = (const float*)d_in[6];
  const float* b_hh0   = (const float*)d_in[7];
  const float* w_ih1   = (const float*)d_in[8];
  const float* w_hh1   = (const float*)d_in[9];
  const float* b_ih1   = (const float*)d_in[10];
  const float* b_hh1   = (const float*)d_in[11];
  const float* fc_w    = (const float*)d_in[12];
  const float* fc_b    = (const float*)d_in[13];
  float* out = (float*)d_out;

  uint8_t* ws = (uint8_t*)d_ws;
  size_t off = 0;
  auto alloc = [&](size_t bytes) {
    uint8_t* p = ws + off;
    off += (bytes + 255) & ~(size_t)255;
    return p;
  };
  float* h0buf          = (float*)alloc((size_t)65536 * 4);
  float* h1buf          = (float*)alloc((size_t)65536 * 4);
  float* wThh0          = (float*)alloc((size_t)2 * 512 * 1536 * 4);
  float* wT1            = (float*)alloc((size_t)2 * 1536 * 1536 * 4);
  unsigned short* embb  = (unsigned short*)alloc((size_t)2097152 * 2);
  unsigned short* wih0b = (unsigned short*)alloc((size_t)1572864 * 2);
  unsigned short* gi0   = (unsigned short*)alloc((size_t)12582912 * 2);
  unsigned short* outsb = (unsigned short*)alloc((size_t)4194304 * 2);
  unsigned short* fcwb  = (unsigned short*)alloc((size_t)32768000 * 2);

  // prep
  cast_bf16<<<dim3(1572864 / 4 / 256), 256, 0, stream>>>(w_ih0, wih0b, 1572864 / 4);
  cast_bf16<<<dim3(32768000 / 4 / 256), 256, 0, stream>>>(fc_w, fcwb, 32768000 / 4);
  for (int d = 0; d < 2; ++d) {
    transpose_f32<<<dim3(512 / 32, 1536 / 32), 256, 0, stream>>>(
        w_hh0 + (size_t)d * 1536 * 512, wThh0 + (size_t)d * 512 * 1536, 1536, 512, 1536, 0);
    transpose_f32<<<dim3(1024 / 32, 1536 / 32), 256, 0, stream>>>(
        w_ih1 + (size_t)d * 1536 * 1024, wT1 + (size_t)d * 1536 * 1536, 1536, 1024, 1536, 0);
    transpose_f32<<<dim3(512 / 32, 1536 / 32), 256, 0, stream>>>(
        w_hh1 + (size_t)d * 1536 * 512, wT1 + (size_t)d * 1536 * 1536, 1536, 512, 1536, 1024);
  }
  embed_gather<<<dim3(4096), 128, 0, stream>>>(target, table, embb);
  init_h<<<dim3(128), 256, 0, stream>>>(context, h0buf, h1buf);

  // gi0 = emb * w_ih0^T + b_ih0   (per d; bf16 out [d][4096][1536])
  gemm_nt<0><<<dim3(32, 12, 2), 256, 0, stream>>>(
      embb, wih0b, b_ih0, gi0, 512, 1536,
      (size_t)1536 * 512, (size_t)4096 * 1536, (size_t)1536);

  // recurrence: skewed pipeline, 129 phases
  for (int p = 0; p <= Ss; ++p) {
    phase_kernel<<<dim3(768), 256, 0, stream>>>(p, gi0, wThh0, wT1, b_hh0, b_ih1, b_hh1,
                                                h0buf, h1buf, outsb);
  }

  // logits = outs * fc_w^T + fc_b  (row remap (s,b)->(b,s))
  gemm_nt<1><<<dim3(32, 250, 1), 256, 0, stream>>>(
      outsb, fcwb, fc_b, out, 1024, Vv, 0, 0, 0);

  // log_softmax in place
  lse_sub<<<dim3(4096), 256, 0, stream>>>(out);
}

// Round 2
// 4146.437 us; speedup vs baseline: 5.1830x; 5.1830x over previous
//
#include <hip/hip_runtime.h>
#include <cstdint>
#include <cstddef>

#define Vv 32000
#define Ee 512
#define Hh 512
#define Bb 32
#define Ss 128

typedef __bf16 bf16x8 __attribute__((ext_vector_type(8)));
typedef float  f32x4  __attribute__((ext_vector_type(4)));

__device__ __forceinline__ float b2f(unsigned short u) {
  union { unsigned int i; float f; } v; v.i = ((unsigned int)u) << 16; return v.f;
}
__device__ __forceinline__ unsigned short f2b(float f) {
  union { float f; unsigned int i; } v; v.f = f;
  unsigned int r = v.i + 0x7FFFu + ((v.i >> 16) & 1u);
  return (unsigned short)(r >> 16);
}
__device__ __forceinline__ float sigm(float x) { return 1.f / (1.f + __expf(-x)); }

// ---------------- prep kernels ----------------

__global__ void zero_flags(unsigned* p) { if (threadIdx.x < 64) p[threadIdx.x] = 0u; }

__global__ void cast_bf16(const float* __restrict__ src, unsigned short* __restrict__ dst, int n4) {
  int i = blockIdx.x * 256 + threadIdx.x;
  if (i >= n4) return;
  float4 v = reinterpret_cast<const float4*>(src)[i];
  ushort4 o;
  o.x = f2b(v.x); o.y = f2b(v.y); o.z = f2b(v.z); o.w = f2b(v.w);
  reinterpret_cast<ushort4*>(dst)[i] = o;
}

// w1cat[d][n][0..1023] = w_ih1[d][n][*]; [1024..1535] = w_hh1[d][n][*]
__global__ void pack_w1(const float* __restrict__ ih, const float* __restrict__ hh,
                        unsigned short* __restrict__ dst) {
  int r = blockIdx.x;  // d*1536 + n
  const float* si = ih + (size_t)r * 1024;
  const float* sh = hh + (size_t)r * 512;
  unsigned short* dr = dst + (size_t)r * 1536;
  for (int c = threadIdx.x; c < 1024; c += 256) dr[c] = f2b(si[c]);
  for (int c = threadIdx.x; c < 512; c += 256) dr[1024 + c] = f2b(sh[c]);
}

// emb_bf16[s][b][e]
__global__ void embed_gather(const int* __restrict__ target, const float* __restrict__ table,
                             unsigned short* __restrict__ emb) {
  int sb = blockIdx.x;           // s*32 + b
  int s = sb >> 5, b = sb & 31;
  int tok = target[b * Ss + s];
  float4 v = reinterpret_cast<const float4*>(table + (size_t)tok * Ee)[threadIdx.x];
  ushort4 o;
  o.x = f2b(v.x); o.y = f2b(v.y); o.z = f2b(v.z); o.w = f2b(v.w);
  reinterpret_cast<ushort4*>(emb + (size_t)sb * Ee)[threadIdx.x] = o;
}

// ---------------- bf16 MFMA GEMM: C = A * B^T + bias ----------------
template <int MODE>
__global__ __launch_bounds__(256, 2) void gemm_nt(
    const unsigned short* __restrict__ A, const unsigned short* __restrict__ Bm,
    const float* __restrict__ bias, void* __restrict__ Cout,
    int K, int ldc, size_t sBz, size_t sCz, size_t sBiasz) {
  int z = blockIdx.z;
  Bm += z * sBz;
  bias += z * sBiasz;

  __shared__ __align__(16) unsigned short As[128 * 64];
  __shared__ __align__(16) unsigned short Bs[128 * 64];

  int t = threadIdx.x;
  int m0 = blockIdx.x * 128, n0 = blockIdx.y * 128;
  int wave = t >> 6, lane = t & 63;
  int wr = wave >> 1, wc = wave & 1;

  f32x4 acc[4][4] = {};

  int kt = K >> 6;
  for (int ks = 0; ks < kt; ++ks) {
    int k0 = ks << 6;
#pragma unroll
    for (int c = 0; c < 4; ++c) {
      int v = c * 256 + t;
      int row = v >> 3, col = (v & 7) * 8;
      uint4 da = *reinterpret_cast<const uint4*>(A + (size_t)(m0 + row) * K + k0 + col);
      uint4 db = *reinterpret_cast<const uint4*>(Bm + (size_t)(n0 + row) * K + k0 + col);
      *reinterpret_cast<uint4*>(As + v * 8) = da;
      *reinterpret_cast<uint4*>(Bs + v * 8) = db;
    }
    __syncthreads();
#pragma unroll
    for (int kk = 0; kk < 2; ++kk) {
      bf16x8 af[4], bfr[4];
      int lrow = lane & 15, lk = kk * 32 + (lane >> 4) * 8;
#pragma unroll
      for (int m = 0; m < 4; ++m)
        af[m] = *reinterpret_cast<const bf16x8*>(As + (wr * 64 + m * 16 + lrow) * 64 + lk);
#pragma unroll
      for (int n = 0; n < 4; ++n)
        bfr[n] = *reinterpret_cast<const bf16x8*>(Bs + (wc * 64 + n * 16 + lrow) * 64 + lk);
#pragma unroll
      for (int m = 0; m < 4; ++m)
#pragma unroll
        for (int n = 0; n < 4; ++n)
          acc[m][n] = __builtin_amdgcn_mfma_f32_16x16x32_bf16(af[m], bfr[n], acc[m][n], 0, 0, 0);
    }
    __syncthreads();
  }

  int lrow4 = (lane >> 4) * 4, lcol = lane & 15;
#pragma unroll
  for (int m = 0; m < 4; ++m) {
    int rbase = m0 + wr * 64 + m * 16 + lrow4;
#pragma unroll
    for (int n = 0; n < 4; ++n) {
      int col = n0 + wc * 64 + n * 16 + lcol;
      float bv = bias[col];
#pragma unroll
      for (int j = 0; j < 4; ++j) {
        int r = rbase + j;
        float vv = acc[m][n][j] + bv;
        if (MODE == 0) {
          ((unsigned short*)Cout)[z * sCz + (size_t)r * ldc + col] = f2b(vv);
        } else {
          int b = r & 31, s = r >> 5;
          ((float*)Cout)[(size_t)(b * Ss + s) * ldc + col] = vv;
        }
      }
    }
  }
}

// ---------------- persistent recurrence kernel ----------------
// grid = 128 blocks x 384 threads. blk<64: layer1 block; blk>=64: layer0 block.
// Each block: d = (blk&63)>>5, owns 16 hidden units j0..j0+15 of its layer.
// XH[par][b][2048] bf16: cols 0..1023 = x = h0(t) [d*512+j], 1024.. = h1(t-1) per d.
// H0[par][d][b][512] bf16 = h0 state for layer0 A-operand.
// One grid barrier per phase (custom, device-scope).

#define MFMA16 __builtin_amdgcn_mfma_f32_16x16x32_bf16

__device__ __forceinline__ void chain2(const unsigned short* __restrict__ a0,
                                       const unsigned short* __restrict__ a1,
                                       const unsigned short* __restrict__ b, int n,
                                       f32x4& c0, f32x4& c1) {
#pragma unroll 4
  for (int i = 0; i < n; ++i) {
    bf16x8 bv = *reinterpret_cast<const bf16x8*>(b + i * 32);
    bf16x8 av0 = *reinterpret_cast<const bf16x8*>(a0 + i * 32);
    bf16x8 av1 = *reinterpret_cast<const bf16x8*>(a1 + i * 32);
    c0 = MFMA16(av0, bv, c0, 0, 0, 0);
    c1 = MFMA16(av1, bv, c1, 0, 0, 0);
  }
}

__global__ __launch_bounds__(384, 1) void pers_kernel(
    const unsigned short* __restrict__ gi0,
    const unsigned short* __restrict__ whh0b, const unsigned short* __restrict__ w1cat,
    const float* __restrict__ b_hh0, const float* __restrict__ b_ih1, const float* __restrict__ b_hh1,
    const float* __restrict__ context,
    unsigned short* __restrict__ XH, unsigned short* __restrict__ H0,
    unsigned short* __restrict__ outs, unsigned* bar) {
  __shared__ float pre[7][16][33];
  __shared__ float hf[32][16];
  __shared__ float bA[16], bB[16], bC[16], bD[16];
  __shared__ unsigned sAbort;

  const int tid = threadIdx.x, blk = blockIdx.x;
  const int w = tid >> 6, lane = tid & 63, ln = lane & 15;
  const int hi8 = (lane >> 4) * 8;
  const bool isL1 = blk < 64;
  const int d = (blk & 63) >> 5, j0 = (blk & 31) * 16;
  const int g = w >> 1, kh = w & 1;

  auto gbar = [&](unsigned expected) -> bool {
    __syncthreads();
    if (tid == 0) {
      __threadfence();
      __hip_atomic_fetch_add(bar, 1u, __ATOMIC_ACQ_REL, __HIP_MEMORY_SCOPE_AGENT);
      unsigned long long t0 = __builtin_amdgcn_s_memrealtime();
      while (__hip_atomic_load(bar, __ATOMIC_ACQUIRE, __HIP_MEMORY_SCOPE_AGENT) < expected) {
        if (__hip_atomic_load(bar + 1, __ATOMIC_RELAXED, __HIP_MEMORY_SCOPE_AGENT) != 0u ||
            (__builtin_amdgcn_s_memrealtime() - t0) > 200000000ULL) {
          __hip_atomic_store(bar + 1, 1u, __ATOMIC_RELEASE, __HIP_MEMORY_SCOPE_AGENT);
          break;
        }
      }
      sAbort = __hip_atomic_load(bar + 1, __ATOMIC_RELAXED, __HIP_MEMORY_SCOPE_AGENT);
      __threadfence();
    }
    __syncthreads();
    return sAbort != 0u;
  };

  auto stile = [&](int s, f32x4 v0, f32x4 v1) {
    int c = ln, r0 = (lane >> 4) * 4;
#pragma unroll
    for (int j = 0; j < 4; ++j) {
      pre[s][c][r0 + j] = v0[j];
      pre[s][c][16 + r0 + j] = v1[j];
    }
  };

  // ---- init: biases + h state ----
  if (tid < 16) {
    int jj = tid;
    if (isL1) {
      bA[jj] = b_ih1[d * 1536 + j0 + jj] + b_hh1[d * 1536 + j0 + jj];
      bB[jj] = b_ih1[d * 1536 + 512 + j0 + jj] + b_hh1[d * 1536 + 512 + j0 + jj];
      bC[jj] = b_ih1[d * 1536 + 1024 + j0 + jj];
      bD[jj] = b_hh1[d * 1536 + 1024 + j0 + jj];
    } else {
      bA[jj] = b_hh0[d * 1536 + j0 + jj];
      bB[jj] = b_hh0[d * 1536 + 512 + j0 + jj];
      bC[jj] = b_hh0[d * 1536 + 1024 + j0 + jj];
    }
  }
  {
    int layer = isL1 ? 1 : 0;
    for (int i = tid; i < 512; i += 384) {
      int jj = i & 15, b = i >> 4;
      float c = context[(((size_t)layer * 2 + d) * 32 + b) * 512 + j0 + jj];
      hf[b][jj] = c;
      unsigned short cb = f2b(c);
      if (isL1) XH[(size_t)b * 2048 + 1024 + d * 512 + j0 + jj] = cb;          // parity 0, h1(-1)
      else      H0[(size_t)32768 + ((size_t)d * 32 + b) * 512 + j0 + jj] = cb; // parity 1, h0(-1)
    }
  }
  if (gbar(128u)) return;

  // ---- phase loop ----
  for (int p = 0; p <= 128; ++p) {
    if (isL1) {
      if (p >= 1) {
        int par = (p - 1) & 1;
        const unsigned short* Bw =
            w1cat + ((size_t)d * 1536 + g * 512 + j0 + ln) * 1536 + kh * 768 + hi8;
        const unsigned short* Ar = XH + (size_t)par * 65536 + (size_t)ln * 2048;
        f32x4 p0 = {}, p1 = {}, q0 = {}, q1 = {};
        int cb = kh * 768 + hi8;
        if (kh == 0) {
          chain2(Ar + cb, Ar + 16 * 2048 + cb, Bw, 24, p0, p1);
        } else {
          chain2(Ar + cb, Ar + 16 * 2048 + cb, Bw, 8, p0, p1);
          int c2 = 1024 + d * 512 + hi8;
          if (g == 2) chain2(Ar + c2, Ar + 16 * 2048 + c2, Bw + 256, 16, q0, q1);
          else        chain2(Ar + c2, Ar + 16 * 2048 + c2, Bw + 256, 16, p0, p1);
        }
        int slot = (g < 2) ? g * 2 + kh : (kh == 0 ? 4 : 5);
        stile(slot, p0, p1);
        if (g == 2 && kh == 1) stile(6, q0, q1);
      }
    } else {
      if (p <= 127) {
        int par2 = (p + 1) & 1;
        const unsigned short* Bw =
            whh0b + ((size_t)d * 1536 + g * 512 + j0 + ln) * 512 + kh * 256 + hi8;
        const unsigned short* Ar =
            H0 + (size_t)par2 * 32768 + ((size_t)d * 32 + ln) * 512 + kh * 256 + hi8;
        f32x4 p0 = {}, p1 = {};
        chain2(Ar, Ar + 16 * 512, Bw, 8, p0, p1);
        int slot = (g < 2) ? g * 2 + kh : 4 + kh;
        stile(slot, p0, p1);
      }
    }
    __syncthreads();
    if (isL1) {
      if (p >= 1) {
        int t_ = p - 1;
        for (int i = tid; i < 512; i += 384) {
          int jj = i & 15, b = i >> 4;
          float r = sigm(pre[0][jj][b] + pre[1][jj][b] + bA[jj]);
          float z = sigm(pre[2][jj][b] + pre[3][jj][b] + bB[jj]);
          float nn = tanhf(pre[4][jj][b] + pre[5][jj][b] + bC[jj] +
                           r * (pre[6][jj][b] + bD[jj]));
          float h = hf[b][jj];
          float hnew = (1.f - z) * nn + z * h;
          hf[b][jj] = hnew;
          unsigned short hb = f2b(hnew);
          XH[(size_t)(p & 1) * 65536 + (size_t)b * 2048 + 1024 + d * 512 + j0 + jj] = hb;
          outs[((size_t)t_ * 32 + b) * 1024 + (size_t)d * 512 + j0 + jj] = hb;
        }
      }
    } else {
      if (p <= 127) {
        const unsigned short* gz = gi0 + ((size_t)d * 128 + p) * 32 * 1536;
        for (int i = tid; i < 512; i += 384) {
          int jj = i & 15, b = i >> 4;
          int col = j0 + jj;
          float gir = b2f(gz[b * 1536 + col]);
          float giz = b2f(gz[b * 1536 + 512 + col]);
          float gin = b2f(gz[b * 1536 + 1024 + col]);
          float r = sigm(gir + pre[0][jj][b] + pre[1][jj][b] + bA[jj]);
          float z = sigm(giz + pre[2][jj][b] + pre[3][jj][b] + bB[jj]);
          float nn = tanhf(gin + r * (pre[4][jj][b] + pre[5][jj][b] + bC[jj]));
          float h = hf[b][jj];
          float hnew = (1.f - z) * nn + z * h;
          hf[b][jj] = hnew;
          unsigned short hb = f2b(hnew);
          H0[(size_t)(p & 1) * 32768 + ((size_t)d * 32 + b) * 512 + col] = hb;
          XH[(size_t)(p & 1) * 65536 + (size_t)b * 2048 + d * 512 + col] = hb;
        }
      }
    }
    if (gbar(128u * (unsigned)(p + 2))) return;
  }
}

// ---------------- fused online logsumexp + subtract ----------------
__global__ __launch_bounds__(256) void lse_sub(float* __restrict__ out) {
  int row = blockIdx.x;
  float* rp = out + (size_t)row * Vv;
  int t = threadIdx.x;
  float m = -1e30f, ssum = 0.f;
  for (int i = t; i < Vv; i += 256) {
    float x = rp[i];
    if (x <= m) {
      ssum += __expf(x - m);
    } else {
      ssum = ssum * __expf(m - x) + 1.f;
      m = x;
    }
  }
  __shared__ float sm[256], ss[256];
  sm[t] = m; ss[t] = ssum;
  __syncthreads();
  for (int off = 128; off > 0; off >>= 1) {
    if (t < off) {
      float m2 = sm[t + off], s2 = ss[t + off];
      float M = fmaxf(sm[t], m2);
      ss[t] = ss[t] * __expf(sm[t] - M) + s2 * __expf(m2 - M);
      sm[t] = M;
    }
    __syncthreads();
  }
  float lse = sm[0] + __logf(ss[0]);
  for (int i = t; i < Vv; i += 256) rp[i] = rp[i] - lse;
}

// ---------------- host ----------------

extern "C" void kernel_launch(void* const* d_in, const int* in_sizes, int n_in,
                              void* d_out, int out_size, void* d_ws, size_t ws_size,
                              hipStream_t stream) {
  (void)in_sizes; (void)n_in; (void)out_size; (void)ws_size;
  const int*   target  = (const int*)  d_in[0];
  const float* context = (const float*)d_in[2];
  const float* table   = (const float*)d_in[3];
  const float* w_ih0   = (const float*)d_in[4];
  const float* w_hh0   = (const float*)d_in[5];
  const float* b_ih0   = (const float*)d_in[6];
  const float* b_hh0   = (const float*)d_in[7];
  const float* w_ih1   = (const float*)d_in[8];
  const float* w_hh1   = (const float*)d_in[9];
  const float* b_ih1   = (const float*)d_in[10];
  const float* b_hh1   = (const float*)d_in[11];
  const float* fc_w    = (const float*)d_in[12];
  const float* fc_b    = (const float*)d_in[13];
  float* out = (float*)d_out;

  uint8_t* ws = (uint8_t*)d_ws;
  size_t off = 0;
  auto alloc = [&](size_t bytes) {
    uint8_t* p = ws + off;
    off += (bytes + 255) & ~(size_t)255;
    return p;
  };
  unsigned*       bar   = (unsigned*)alloc(256);
  unsigned short* XH    = (unsigned short*)alloc((size_t)2 * 32 * 2048 * 2);
  unsigned short* H0    = (unsigned short*)alloc((size_t)2 * 2 * 32 * 512 * 2);
  unsigned short* whh0b = (unsigned short*)alloc((size_t)1572864 * 2);
  unsigned short* w1cat = (unsigned short*)alloc((size_t)2 * 1536 * 1536 * 2);
  unsigned short* embb  = (unsigned short*)alloc((size_t)2097152 * 2);
  unsigned short* wih0b = (unsigned short*)alloc((size_t)1572864 * 2);
  unsigned short* gi0   = (unsigned short*)alloc((size_t)12582912 * 2);
  unsigned short* outsb = (unsigned short*)alloc((size_t)4194304 * 2);
  unsigned short* fcwb  = (unsigned short*)alloc((size_t)32768000 * 2);

  // prep
  zero_flags<<<dim3(1), 64, 0, stream>>>(bar);
  cast_bf16<<<dim3(1536), 256, 0, stream>>>(w_ih0, wih0b, 393216);
  cast_bf16<<<dim3(1536), 256, 0, stream>>>(w_hh0, whh0b, 393216);
  cast_bf16<<<dim3(32000), 256, 0, stream>>>(fc_w, fcwb, 8192000);
  pack_w1<<<dim3(3072), 256, 0, stream>>>(w_ih1, w_hh1, w1cat);
  embed_gather<<<dim3(4096), 128, 0, stream>>>(target, table, embb);

  // gi0 = emb * w_ih0^T + b_ih0  (bf16 out [d][4096][1536])
  gemm_nt<0><<<dim3(32, 12, 2), 256, 0, stream>>>(
      embb, wih0b, b_ih0, gi0, 512, 1536,
      (size_t)1536 * 512, (size_t)4096 * 1536, (size_t)1536);

  // recurrence: one persistent kernel, 130 grid barriers
  pers_kernel<<<dim3(128), 384, 0, stream>>>(
      gi0, whh0b, w1cat, b_hh0, b_ih1, b_hh1, context, XH, H0, outsb, bar);

  // logits = outs * fc_w^T + fc_b  (row remap (s,b)->(b,s))
  gemm_nt<1><<<dim3(32, 250, 1), 256, 0, stream>>>(
      outsb, fcwb, fc_b, out, 1024, Vv, 0, 0, 0);

  // log_softmax in place
  lse_sub<<<dim3(4096), 256, 0, stream>>>(out);
}